// Round 8
// baseline (59.492 us; speedup 1.0000x reference)
//
#include <hip/hip_runtime.h>
#include <hip/hip_bf16.h>

#define NUM_OPS 8
#define D 1024
#define B_ROWS 8192

typedef unsigned short ushort_t;
typedef __attribute__((ext_vector_type(8))) short bf16x8;
typedef __attribute__((ext_vector_type(4))) float f32x4;
typedef __attribute__((ext_vector_type(4))) float float4v;
typedef __attribute__((ext_vector_type(8))) unsigned short ushort8;

__device__ __forceinline__ unsigned short f2bf(float f) {
    union { float f; unsigned int u; } v; v.f = f;
    unsigned int u = v.u;
    unsigned int lsb = (u >> 16) & 1u;
    u += 0x7fffu + lsb;   // round-to-nearest-even
    return (unsigned short)(u >> 16);
}

// ---------------- top-2 selection ----------------
__global__ void topk_kernel(const float* __restrict__ logits, int* __restrict__ idx) {
    if (threadIdx.x == 0 && blockIdx.x == 0) {
        float best = -__builtin_inff(); int bi = 0;
        for (int i = 0; i < NUM_OPS; ++i) {
            float v = logits[i];
            if (v > best) { best = v; bi = i; }
        }
        float best2 = -__builtin_inff(); int bi2 = 0;
        for (int i = 0; i < NUM_OPS; ++i) {
            if (i == bi) continue;
            float v = logits[i];
            if (v > best2) { best2 = v; bi2 = i; }
        }
        idx[0] = bi; idx[1] = bi2;
    }
}

// -------- x: f32 -> bf16, reordered into MFMA A-fragment layout ------------
// Af byte addr of (r,u,f,lane): r*131072 + u*8192 + f*1024 + lane*16
// holding x[r*64 + (f&3)*16 + (lane&15)][u*64 + (f>>2)*32 + (lane>>4)*8 + j]
__global__ void convert_frag_x(const float* __restrict__ x, ushort_t* __restrict__ Af) {
    __shared__ float t[64][65];
    const int b = blockIdx.x;            // r*16 + u
    const int r = b >> 4, u = b & 15;
    const int tid = threadIdx.x;

    const int row = tid >> 2, c0 = (tid & 3) * 16;
    const float* src = x + (size_t)(r * 64 + row) * D + u * 64 + c0;
    #pragma unroll
    for (int j = 0; j < 4; ++j) {
        float4v v = *(const float4v*)(src + j * 4);
        t[row][c0 + j * 4 + 0] = v[0];
        t[row][c0 + j * 4 + 1] = v[1];
        t[row][c0 + j * 4 + 2] = v[2];
        t[row][c0 + j * 4 + 3] = v[3];
    }
    __syncthreads();

    #pragma unroll
    for (int g2 = 0; g2 < 2; ++g2) {
        const int g = g2 * 256 + tid;
        const int f = g >> 6, lane = g & 63;     // f = kk*4 + m
        const int kk = f >> 2, m = f & 3;
        const int rr = m * 16 + (lane & 15);
        const int cc = kk * 32 + (lane >> 4) * 8;
        ushort8 o;
        #pragma unroll
        for (int j = 0; j < 8; ++j) o[j] = f2bf(t[rr][cc + j]);
        *(ushort8*)(Af + ((size_t)(r * 16 + u) * 8 + f) * 512 + lane * 8) = o;
    }
}

// ------- gather selected experts' W into MFMA B-fragment layout ------------
// Wf byte addr of (e,p,u,kn,lane): e*2097152 + p*65536 + u*4096 + kn*1024 + lane*16
// kn = kk*2 + n16, holding W[u*64+kk*32+(lane>>4)*8+j][p*32+n16*16+(lane&15)]
__global__ void gather_frag_W(const float* __restrict__ Ws,
                              const int* __restrict__ idx,
                              ushort_t* __restrict__ Wf) {
    __shared__ float t[32][33];
    const int b  = blockIdx.x;              // ((e*32 + kt)*32 + nt)
    const int nt = b & 31, kt = (b >> 5) & 31, e = b >> 10;
    const int td = kt * 32, te = nt * 32;
    const int tx = threadIdx.x & 31, ty = threadIdx.x >> 5;
    const float* W = Ws + (size_t)idx[e] * D * D;
    #pragma unroll
    for (int r = 0; r < 4; ++r)
        t[ty + 8 * r][tx] = W[(size_t)(td + ty + 8 * r) * D + te + tx];
    __syncthreads();
    const int vid = threadIdx.x;
    if (vid < 128) {
        const int n_l = vid & 31, kg = vid >> 5;
        const int n = te + n_l, k0 = td + kg * 8;
        const int u = k0 >> 6, kk = (k0 >> 5) & 1, lq = (k0 >> 3) & 3;
        const int p = n >> 5, n16 = (n >> 4) & 1, l15 = n & 15;
        const int lane = lq * 16 + l15;
        const int fi = (((e * 32 + p) * 16 + u) * 2 + kk) * 2 + n16;
        ushort8 o;
        #pragma unroll
        for (int j = 0; j < 8; ++j) o[j] = f2bf(t[kg * 8 + j][n_l]);
        *(ushort8*)(Wf + (size_t)fi * 512 + lane * 8) = o;
    }
}

#define SB()    __builtin_amdgcn_sched_barrier(0)
#define PRIO1() __builtin_amdgcn_s_setprio(1)
#define PRIO0() __builtin_amdgcn_s_setprio(0)
#define VMW(N)  do { asm volatile("s_waitcnt vmcnt(" #N ")" ::: "memory"); SB(); } while (0)

// inline-asm load: compiler cannot re-serialize or auto-waitcnt these.
#define GLD(dst, off, base, imm)                                               \
    asm volatile("global_load_dwordx4 %0, %1, %2 offset:" #imm                 \
                 : "=v"(dst) : "v"(off), "s"(base) : "memory")

// issue one K-tile's 16 fragment loads (A: 8, B: 8) into named set P
#define ISSUE(P, u)                                                            \
    do {                                                                       \
        unsigned vA  = aoff + (unsigned)(u) * 8192u;                           \
        unsigned vA2 = vA + 4096u;                                             \
        unsigned vB  = boff + (unsigned)(u) * 4096u;                           \
        unsigned vB2 = vB + 2097152u;                                          \
        GLD(P##a0, vA,  Af, 0);    GLD(P##a1, vA,  Af, 1024);                  \
        GLD(P##a2, vA,  Af, 2048); GLD(P##a3, vA,  Af, 3072);                  \
        GLD(P##a4, vA2, Af, 0);    GLD(P##a5, vA2, Af, 1024);                  \
        GLD(P##a6, vA2, Af, 2048); GLD(P##a7, vA2, Af, 3072);                  \
        GLD(P##b0, vB,  Wf, 0);    GLD(P##b1, vB,  Wf, 1024);                  \
        GLD(P##b2, vB,  Wf, 2048); GLD(P##b3, vB,  Wf, 3072);                  \
        GLD(P##b4, vB2, Wf, 0);    GLD(P##b5, vB2, Wf, 1024);                  \
        GLD(P##b6, vB2, Wf, 2048); GLD(P##b7, vB2, Wf, 3072);                  \
    } while (0)

#define MF(a, b, c) __builtin_amdgcn_mfma_f32_16x16x32_bf16(a, b, c, 0, 0, 0)
#define Q(P, A, B, E, M, N) acc[E][M][N] = MF(P##A, P##B, acc[E][M][N])

// 32 MFMA on set P. a index = kk*4+m ; b index = e*4 + kk*2 + n16
#define MFMA_SET(P)                                                            \
    do {                                                                       \
        PRIO1();                                                               \
        Q(P,a0,b0,0,0,0); Q(P,a0,b1,0,0,1); Q(P,a0,b4,1,0,0); Q(P,a0,b5,1,0,1);\
        Q(P,a1,b0,0,1,0); Q(P,a1,b1,0,1,1); Q(P,a1,b4,1,1,0); Q(P,a1,b5,1,1,1);\
        Q(P,a2,b0,0,2,0); Q(P,a2,b1,0,2,1); Q(P,a2,b4,1,2,0); Q(P,a2,b5,1,2,1);\
        Q(P,a3,b0,0,3,0); Q(P,a3,b1,0,3,1); Q(P,a3,b4,1,3,0); Q(P,a3,b5,1,3,1);\
        Q(P,a4,b2,0,0,0); Q(P,a4,b3,0,0,1); Q(P,a4,b6,1,0,0); Q(P,a4,b7,1,0,1);\
        Q(P,a5,b2,0,1,0); Q(P,a5,b3,0,1,1); Q(P,a5,b6,1,1,0); Q(P,a5,b7,1,1,1);\
        Q(P,a6,b2,0,2,0); Q(P,a6,b3,0,2,1); Q(P,a6,b6,1,2,0); Q(P,a6,b7,1,2,1);\
        Q(P,a7,b2,0,3,0); Q(P,a7,b3,0,3,1); Q(P,a7,b6,1,3,0); Q(P,a7,b7,1,3,1);\
        PRIO0();                                                               \
    } while (0)

// ---------------- fused dual-expert GEMM: asm-forced 2-deep pipeline --------
// No LDS, no barriers. 4 independent waves/block (2r x 2p); wave tile
// 64 rows x 32 cols x 2 experts. All K-loop loads are inline-asm
// global_load_dwordx4 with manual counted vmcnt(16): tile u+1 always in
// flight while tile u computes (621 cyc MFMA cover per 16-load set).
__global__ __launch_bounds__(256, 2)
void gemm_frag(const ushort_t* __restrict__ Af, const ushort_t* __restrict__ Wf,
               const float* __restrict__ bs, const int* __restrict__ idx,
               float* __restrict__ out) {
    const int tid  = threadIdx.x;
    const int wv   = tid >> 6;
    const int lane = tid & 63;
    const int l15  = lane & 15, lq = lane >> 4;

    const int r = (blockIdx.x & 63) * 2 + (wv & 1);    // 0..127 row-block
    const int p = (blockIdx.x >> 6) * 2 + (wv >> 1);   // 0..31 col-panel

    const unsigned aoff = (unsigned)r * 131072u + (unsigned)lane * 16u;
    const unsigned boff = (unsigned)p * 65536u  + (unsigned)lane * 16u;

    f32x4 acc[2][4][2] = {};

    bf16x8 Xa0, Xa1, Xa2, Xa3, Xa4, Xa5, Xa6, Xa7;
    bf16x8 Xb0, Xb1, Xb2, Xb3, Xb4, Xb5, Xb6, Xb7;
    bf16x8 Ya0, Ya1, Ya2, Ya3, Ya4, Ya5, Ya6, Ya7;
    bf16x8 Yb0, Yb1, Yb2, Yb3, Yb4, Yb5, Yb6, Yb7;

    ISSUE(X, 0); SB();
    ISSUE(Y, 1); SB();

    #pragma unroll 1
    for (int u = 0; u < 14; u += 2) {
        VMW(16);              // X (tile u) landed; Y still in flight
        MFMA_SET(X); SB();
        ISSUE(X, u + 2); SB();
        VMW(16);              // Y (tile u+1) landed; new X in flight
        MFMA_SET(Y); SB();
        ISSUE(Y, u + 3); SB();
    }
    VMW(16);                  // tile 14
    MFMA_SET(X); SB();
    VMW(0);                   // tile 15
    MFMA_SET(Y); SB();

    // ---- epilogue: per-expert bias + relu, sum, store f32
    const int i0 = idx[0], i1 = idx[1];
    #pragma unroll
    for (int n16 = 0; n16 < 2; ++n16) {
        const int col = p * 32 + n16 * 16 + l15;
        const float b0 = bs[i0 * D + col];
        const float b1 = bs[i1 * D + col];
        #pragma unroll
        for (int m = 0; m < 4; ++m) {
            const int rbase = r * 64 + m * 16 + lq * 4;
            #pragma unroll
            for (int i = 0; i < 4; ++i) {
                float v0 = acc[0][m][n16][i] + b0; v0 = v0 > 0.f ? v0 : 0.f;
                float v1 = acc[1][m][n16][i] + b1; v1 = v1 > 0.f ? v1 : 0.f;
                out[(size_t)(rbase + i) * D + col] = v0 + v1;
            }
        }
    }
}

extern "C" void kernel_launch(void* const* d_in, const int* in_sizes, int n_in,
                              void* d_out, int out_size, void* d_ws, size_t ws_size,
                              hipStream_t stream) {
    const float* x      = (const float*)d_in[0];
    const float* logits = (const float*)d_in[1];
    const float* Ws     = (const float*)d_in[2];
    const float* bs     = (const float*)d_in[3];
    float* out = (float*)d_out;

    char* ws = (char*)d_ws;
    ushort_t* Af = (ushort_t*)ws;                                    // 16 MB
    ushort_t* Wf = (ushort_t*)(ws + (size_t)B_ROWS * D * 2);         //  4 MB
    int* idx     = (int*)(ws + (size_t)B_ROWS * D * 2 + (size_t)2 * D * D * 2);

    topk_kernel<<<1, 1, 0, stream>>>(logits, idx);
    convert_frag_x<<<128 * 16, 256, 0, stream>>>(x, Af);
    gather_frag_W<<<2 * 32 * 32, 256, 0, stream>>>(Ws, idx, Wf);

    gemm_frag<<<1024, 256, 0, stream>>>(Af, Wf, bs, idx, out);
}

// Round 9
// 52.658 us; speedup vs baseline: 1.1298x; 1.1298x over previous
//
#include <hip/hip_runtime.h>
#include <hip/hip_bf16.h>

#define NUM_OPS 8
#define D 1024
#define B_ROWS 8192

typedef unsigned short ushort_t;
typedef __attribute__((ext_vector_type(8))) short bf16x8;
typedef __attribute__((ext_vector_type(4))) float f32x4;
typedef __attribute__((ext_vector_type(4))) float float4v;
typedef __attribute__((ext_vector_type(8))) unsigned short ushort8;

__device__ __forceinline__ unsigned short f2bf(float f) {
    union { float f; unsigned int u; } v; v.f = f;
    unsigned int u = v.u;
    unsigned int lsb = (u >> 16) & 1u;
    u += 0x7fffu + lsb;   // round-to-nearest-even
    return (unsigned short)(u >> 16);
}

__device__ __forceinline__ void load_lds16(const void* g, void* l) {
    __builtin_amdgcn_global_load_lds(
        (const __attribute__((address_space(1))) void*)g,
        (__attribute__((address_space(3))) void*)l,
        16, 0, 0);
}

// deterministic top-2 (matches jax top_k tie-breaking: earliest index wins)
__device__ __forceinline__ void top2(const float* __restrict__ logits, int& i0, int& i1) {
    float best = -__builtin_inff(); i0 = 0;
    for (int i = 0; i < NUM_OPS; ++i) { float v = logits[i]; if (v > best) { best = v; i0 = i; } }
    float best2 = -__builtin_inff(); i1 = 0;
    for (int i = 0; i < NUM_OPS; ++i) {
        if (i == i0) continue;
        float v = logits[i]; if (v > best2) { best2 = v; i1 = i; }
    }
}

// ---------------- x : f32 -> bf16 (linear row-major) ----------------
__global__ void convert_x(const float* __restrict__ x, ushort_t* __restrict__ xb) {
    int i = (blockIdx.x * 256 + threadIdx.x) * 8;
    float4v v0 = *(const float4v*)(x + i);
    float4v v1 = *(const float4v*)(x + i + 4);
    ushort8 o;
    o[0] = f2bf(v0[0]); o[1] = f2bf(v0[1]); o[2] = f2bf(v0[2]); o[3] = f2bf(v0[3]);
    o[4] = f2bf(v1[0]); o[5] = f2bf(v1[1]); o[6] = f2bf(v1[2]); o[7] = f2bf(v1[3]);
    *(ushort8*)(xb + i) = o;
}

// ------- gather selected experts' W, transpose to [n][k], cast bf16 -------
// Wt[e][n*D + k] = (bf16) Ws[sel_e][k*D + n]   (top-2 computed inline)
__global__ void gather_transpose_W(const float* __restrict__ Ws,
                                   const float* __restrict__ logits,
                                   ushort_t* __restrict__ Wt) {
    __shared__ float t[32][33];
    int i0, i1; top2(logits, i0, i1);
    int e    = blockIdx.x >> 10;
    int tile = blockIdx.x & 1023;
    int td = (tile >> 5) << 5;
    int te = (tile & 31) << 5;
    int tx = threadIdx.x & 31, ty = threadIdx.x >> 5;
    const float* W = Ws + (size_t)(e ? i1 : i0) * D * D;
    for (int r = 0; r < 4; ++r)
        t[ty + 8 * r][tx] = W[(size_t)(td + ty + 8 * r) * D + te + tx];
    __syncthreads();
    ushort_t* o = Wt + (size_t)e * D * D;
    for (int r = 0; r < 4; ++r)
        o[(size_t)(te + ty + 8 * r) * D + td + tx] = f2bf(t[tx][ty + 8 * r]);
}

// -------- staging: linear LDS dest, inverse-XOR-swizzled global source -----
// LDS row = 128B; LDS byte (r*128 + c') holds global col-byte (c' ^ ((r&7)<<4)).
__device__ __forceinline__ void stageA(const ushort_t* __restrict__ xbf, int brow,
                                       int u, ushort_t* dst, int tid) {
    #pragma unroll
    for (int q = 0; q < 4; ++q) {                       // 256 rows x 128B = 32KB
        const int c   = q * 512 + tid;
        const int rr  = c >> 3;
        const int gcb = ((c & 7) * 16) ^ ((rr & 7) << 4);
        load_lds16(xbf + (size_t)(brow + rr) * D + u * 64 + (gcb >> 1), dst + c * 8);
    }
}
__device__ __forceinline__ void stageB(const ushort_t* __restrict__ Wt, int bcol,
                                       int u, ushort_t* dst, int tid) {
    #pragma unroll
    for (int q = 0; q < 2; ++q) {                       // 2e x 64 rows x 128B = 16KB
        const int c   = q * 512 + tid;
        const int e   = c >> 9, cc = c & 511;
        const int n   = cc >> 3;
        const int gcb = ((cc & 7) * 16) ^ ((n & 7) << 4);
        load_lds16(Wt + (size_t)e * D * D + (size_t)(bcol + n) * D + u * 64 + (gcb >> 1),
                   dst + c * 8);
    }
}

#define SB()    __builtin_amdgcn_sched_barrier(0)
#define PRIO1() __builtin_amdgcn_s_setprio(1)
#define PRIO0() __builtin_amdgcn_s_setprio(0)

// one K-tile: [stage(u+2) | ds_read(u) | 32 MFMA | vmcnt(N) | s_barrier]
// No vmcnt(0) in steady state: the waited loads are a full tile old (free).
#define TILE(CA, CB, DA, DB, SU, VMN, DOSTG, DOBAR)                                \
    do {                                                                           \
        if (DOSTG) { stageA(xbf, brow, (SU), DA, tid);                             \
                     stageB(Wt,  bcol, (SU), DB, tid); }                           \
        SB();                                                                      \
        bf16x8 a[2][4], b[2][2][2];                                                \
        _Pragma("unroll") for (int kk = 0; kk < 2; ++kk)                           \
        _Pragma("unroll") for (int m = 0; m < 4; ++m)                              \
            a[kk][m] = *(const bf16x8*)((const char*)(CA) +                        \
                (size_t)((rgrp * 64 + m * 16 + l15) * 128) + (kk ? x1 : x0));      \
        _Pragma("unroll") for (int e = 0; e < 2; ++e)                              \
        _Pragma("unroll") for (int kk = 0; kk < 2; ++kk)                           \
        _Pragma("unroll") for (int n16 = 0; n16 < 2; ++n16)                        \
            b[e][kk][n16] = *(const bf16x8*)((const char*)(CB) + e * 8192 +        \
                (size_t)((cgrp * 32 + n16 * 16 + l15) * 128) + (kk ? x1 : x0));    \
        PRIO1();                                                                   \
        _Pragma("unroll") for (int kk = 0; kk < 2; ++kk)                           \
        _Pragma("unroll") for (int e = 0; e < 2; ++e)                              \
        _Pragma("unroll") for (int m = 0; m < 4; ++m)                              \
        _Pragma("unroll") for (int n16 = 0; n16 < 2; ++n16)                        \
            acc[e][m][n16] = __builtin_amdgcn_mfma_f32_16x16x32_bf16(              \
                a[kk][m], b[e][kk][n16], acc[e][m][n16], 0, 0, 0);                 \
        PRIO0();                                                                   \
        SB();                                                                      \
        asm volatile("s_waitcnt vmcnt(" #VMN ")" ::: "memory");                    \
        if (DOBAR) __builtin_amdgcn_s_barrier();                                   \
    } while (0)

// -------- fused dual-expert GEMM: 3-buffer LDS rotation, counted vmcnt -----
// Block: 256 rows x 64 cols x 2 experts, 8 waves (4r x 2c), BK=64.
// Wave: 64r x 32c x 2e -> acc 64 VGPR. LDS 144KB = 3 x (A 32KB + B 16KB).
// Tile u reads buf[u%3]; stages tile u+2 into buf[(u+2)%3]; vmcnt(6) at tile
// end keeps the 6 newest stage-loads in flight across the raw s_barrier.
__global__ __launch_bounds__(512, 2)
void gemm_dual(const ushort_t* __restrict__ xbf, const ushort_t* __restrict__ Wt,
               const float* __restrict__ bs, const float* __restrict__ logits,
               float* __restrict__ out) {
    __shared__ __align__(16) ushort_t As0[256 * 64], As1[256 * 64], As2[256 * 64];
    __shared__ __align__(16) ushort_t Bs0[2 * 64 * 64], Bs1[2 * 64 * 64], Bs2[2 * 64 * 64];

    const int tid  = threadIdx.x;
    const int wv   = tid >> 6;
    const int lane = tid & 63;
    const int rgrp = wv >> 1, cgrp = wv & 1;
    const int l15  = lane & 15, lq = lane >> 4;
    const int swz  = (l15 & 7) << 4;
    const int x0   = (lq * 16) ^ swz;
    const int x1   = (64 + lq * 16) ^ swz;

    // rows vary fastest across bids: XCD x keeps row-stripes {x, x+8, ...}
    const int bid  = blockIdx.x;
    const int brow = (bid & 31) * 256;
    const int bcol = (bid >> 5) * 64;

    f32x4 acc[2][4][2] = {};

    // prologue: stage tiles 0,1 (12 loads); wait for tile 0's 6
    stageA(xbf, brow, 0, As0, tid); stageB(Wt, bcol, 0, Bs0, tid);
    stageA(xbf, brow, 1, As1, tid); stageB(Wt, bcol, 1, Bs1, tid);
    SB();
    asm volatile("s_waitcnt vmcnt(6)" ::: "memory");
    __builtin_amdgcn_s_barrier();

    TILE(As0, Bs0, As2, Bs2,  2, 6, true,  true);   // u=0
    TILE(As1, Bs1, As0, Bs0,  3, 6, true,  true);   // u=1
    TILE(As2, Bs2, As1, Bs1,  4, 6, true,  true);   // u=2
    TILE(As0, Bs0, As2, Bs2,  5, 6, true,  true);   // u=3
    TILE(As1, Bs1, As0, Bs0,  6, 6, true,  true);   // u=4
    TILE(As2, Bs2, As1, Bs1,  7, 6, true,  true);   // u=5
    TILE(As0, Bs0, As2, Bs2,  8, 6, true,  true);   // u=6
    TILE(As1, Bs1, As0, Bs0,  9, 6, true,  true);   // u=7
    TILE(As2, Bs2, As1, Bs1, 10, 6, true,  true);   // u=8
    TILE(As0, Bs0, As2, Bs2, 11, 6, true,  true);   // u=9
    TILE(As1, Bs1, As0, Bs0, 12, 6, true,  true);   // u=10
    TILE(As2, Bs2, As1, Bs1, 13, 6, true,  true);   // u=11
    TILE(As0, Bs0, As2, Bs2, 14, 6, true,  true);   // u=12
    TILE(As1, Bs1, As0, Bs0, 15, 6, true,  true);   // u=13
    TILE(As2, Bs2, As0, Bs0,  0, 0, false, true);   // u=14 (drain s15)
    TILE(As0, Bs0, As1, Bs1,  0, 0, false, false);  // u=15

    // ---- epilogue: per-expert bias + relu, sum, store f32
    int i0, i1; top2(logits, i0, i1);
    #pragma unroll
    for (int n16 = 0; n16 < 2; ++n16) {
        const int col = bcol + cgrp * 32 + n16 * 16 + l15;
        const float b0 = bs[i0 * D + col];
        const float b1 = bs[i1 * D + col];
        #pragma unroll
        for (int m = 0; m < 4; ++m) {
            const int rbase = brow + rgrp * 64 + m * 16 + lq * 4;
            #pragma unroll
            for (int i = 0; i < 4; ++i) {
                float v0 = acc[0][m][n16][i] + b0; v0 = v0 > 0.f ? v0 : 0.f;
                float v1 = acc[1][m][n16][i] + b1; v1 = v1 > 0.f ? v1 : 0.f;
                out[(size_t)(rbase + i) * D + col] = v0 + v1;
            }
        }
    }
}

extern "C" void kernel_launch(void* const* d_in, const int* in_sizes, int n_in,
                              void* d_out, int out_size, void* d_ws, size_t ws_size,
                              hipStream_t stream) {
    const float* x      = (const float*)d_in[0];
    const float* logits = (const float*)d_in[1];
    const float* Ws     = (const float*)d_in[2];
    const float* bs     = (const float*)d_in[3];
    float* out = (float*)d_out;

    char* ws = (char*)d_ws;
    ushort_t* xbf = (ushort_t*)ws;                                   // 16 MB
    ushort_t* Wt  = (ushort_t*)(ws + (size_t)B_ROWS * D * 2);        //  4 MB

    convert_x<<<(B_ROWS * D) / (256 * 8), 256, 0, stream>>>(x, xbf);
    gather_transpose_W<<<2 * (D / 32) * (D / 32), 256, 0, stream>>>(Ws, logits, Wt);

    gemm_dual<<<512, 512, 0, stream>>>(xbf, Wt, bs, logits, out);
}